// Round 12
// baseline (137.641 us; speedup 1.0000x reference)
//
#include <hip/hip_runtime.h>
#include <stdint.h>

#define B_ROWS 4096
#define OUTF   1024
#define INF    1024
#define KX     1024          // K-extent of x (powers handled in-register)
#define BN_EPS 1e-5f
#define BM 128
#define BN 128
#define BK 32
#define NSTEP (KX / BK)      // 32

typedef short  short8  __attribute__((ext_vector_type(8)));
typedef float  floatx4 __attribute__((ext_vector_type(4)));

struct alignas(8) s4 { short x, y, z, w; };

// s_waitcnt SIMM16 (gfx9/gfx950): vmcnt[3:0]=imm[3:0], expcnt=imm[6:4],
// lgkmcnt=imm[11:8], vmcnt[5:4]=imm[15:14].
#define WAIT_VM8 0x0F78
#define WAIT_VM4 0x0F74
#define WAIT_VM0 0x0F70

__device__ __forceinline__ short f2bf(float f) {
  union { float f; uint32_t u; } cv; cv.f = f;
  uint32_t u = cv.u;
  uint32_t r = (u + 0x7fffu + ((u >> 16) & 1u)) >> 16;  // RNE
  return (short)r;
}

__device__ __forceinline__ void load_lds16(const void* g, void* l) {
  __builtin_amdgcn_global_load_lds(
      (const __attribute__((address_space(1))) uint32_t*)(uintptr_t)g,
      (__attribute__((address_space(3))) uint32_t*)(uint32_t)(uintptr_t)l,
      16, 0, 0);
}

// pack two f32 into packed bf16x2 with round-half-up (1 add each)
__device__ __forceinline__ uint32_t pack2(float hi, float lo) {
  union { float f; uint32_t u; } H, L; H.f = hi; L.f = lo;
  return ((H.u + 0x8000u) & 0xffff0000u) | ((L.u + 0x8000u) >> 16);
}

// element-wise square/cube of a bf16x8 MFMA A-fragment (positional layout:
// powers of the x-fragment ARE the fragments of the x^2/x^3 K-sections)
__device__ __forceinline__ void frag_pows(const short8 a, short8* a2, short8* a3) {
  const uint32_t* ap = (const uint32_t*)&a;
  uint32_t* p2 = (uint32_t*)a2;
  uint32_t* p3 = (uint32_t*)a3;
  #pragma unroll
  for (int h = 0; h < 4; ++h) {
    uint32_t u = ap[h];
    union { uint32_t u; float f; } lo, hi;
    lo.u = u << 16; hi.u = u & 0xffff0000u;
    float l2 = lo.f * lo.f, h2 = hi.f * hi.f;
    float l3 = l2 * lo.f,  h3 = h2 * hi.f;
    p2[h] = pack2(h2, l2);
    p3[h] = pack2(h3, l3);
  }
}

// ---- 1. prep: x -> bf16 Xb[4096][1024]; c1/c2/c3 -> bf16 planes Wb[3][1024][1024]
// bias skipped: a per-column constant shifts the batch mean and is cancelled
// exactly by BatchNorm (variance unaffected). [verified R6..R11]
__global__ void prep_all(const float4* __restrict__ x4,
                         const float4* __restrict__ c1, const float4* __restrict__ c2,
                         const float4* __restrict__ c3,
                         short* __restrict__ Xb, short* __restrict__ Wb) {
  int b = blockIdx.x;
  if (b < 4096) {
    int idx = b * 256 + threadIdx.x;           // 1,048,576 float4 of x
    float4 v = x4[idx];
    int row = idx >> 8;
    int c   = (idx & 255) << 2;
    s4 p1 = { f2bf(v.x), f2bf(v.y), f2bf(v.z), f2bf(v.w) };
    *(s4*)&Xb[(size_t)row * KX + c] = p1;
  } else {
    int idx = (b - 4096) * 256 + threadIdx.x;  // 262,144 float4 per weight
    int row = idx >> 8;
    int c   = (idx & 255) << 2;
    size_t base = (size_t)row * KX + c;
    float4 a = c1[idx], bb = c2[idx], d = c3[idx];
    s4 p1 = { f2bf(a.x),  f2bf(a.y),  f2bf(a.z),  f2bf(a.w)  };
    s4 p2 = { f2bf(bb.x), f2bf(bb.y), f2bf(bb.z), f2bf(bb.w) };
    s4 p3 = { f2bf(d.x),  f2bf(d.y),  f2bf(d.z),  f2bf(d.w)  };
    *(s4*)&Wb[base]           = p1;
    *(s4*)&Wb[base + 1048576] = p2;
    *(s4*)&Wb[base + 2097152] = p3;
  }
}

// ---- 2. GEMM 128x128 over KX=1024, powers in-register ----------------------
// Per step: stage 1 x-tile (8 KB) + 3 W-tiles (24 KB); A-frags for c2/c3 are
// computed in-register as element-wise powers (staged bytes: 403 -> 268 MB).
// 4 LDS buffers x 32 KB = 128 KB, 3-deep prefetch, wait vmcnt(8) + raw
// s_barrier (tiles s+1,s+2 = 8 loads stay in flight). Prefetch s+3 into buf
// (s+3)%4 = (s-1)%4 — consumed last step, safe after this step's barrier.
// LDS swizzle (R1-verified, 0 conflicts): BK=32 rows = 4 slots of 16 B;
// physical slot p of row r holds logical slot p ^ ((r>>1) & 3).
__global__ __launch_bounds__(512, 2) void gemm_poly(
    const short* __restrict__ Xb, const short* __restrict__ Wb,
    float* __restrict__ Y, float* __restrict__ psum, float* __restrict__ psq) {
  __shared__ __align__(16) short As[4][BM * BK];       // 4 x 8 KB
  __shared__ __align__(16) short Bs[4][3 * BN * BK];   // 4 x 24 KB (128 KB tot)
  const int tid  = threadIdx.x;
  const int lane = tid & 63;
  const int wave = tid >> 6;
  const int wr = wave >> 2;            // 0..1 : 64-row half
  const int wc = wave & 3;             // 0..3 : 32-col quarter
  const int lb  = blockIdx.x;
  const int xcd = lb & 7;
  const int sl  = lb >> 3;             // 0..31
  const int bx  = sl & 7;              // col-block 0..7
  const int by  = xcd * 4 + (sl >> 3); // row-strip 0..31
  const int row0 = by * BM;
  const int col0 = bx * BN;
  const int frag_m = lane & 15;
  const int sel = lane >> 4;           // 16B k-slot within the K=32 step
  floatx4 acc[4][2] = {};

  // staging: thread tid owns physical chunk tid of the A-tile and chunk tid
  // of each W-plane tile. row r = tid>>2, slot p = tid&3, logical slot
  // l = p ^ ((r>>1)&3); A src = Xb[row0+r][kt + l*8], W src plane pi adds
  // pi*1048576. LDS dst = chunk tid (contiguous per wave - required by
  // global_load_lds).
  const int r_  = tid >> 2;
  const int l_  = (tid & 3) ^ ((r_ >> 1) & 3);
  const int aoff = (row0 + r_) * KX + l_ * 8;
  const size_t boff = (size_t)(col0 + r_) * KX + l_ * 8;
  const int ldst = tid * 8;

  // prologue: stage tiles 0,1,2 into bufs 0,1,2 (4 loads/thread/tile)
  #pragma unroll
  for (int t = 0; t < 3; ++t) {
    load_lds16(Xb + aoff + t * BK, &As[t][ldst]);
    #pragma unroll
    for (int pi = 0; pi < 3; ++pi)
      load_lds16(Wb + boff + pi * 1048576 + t * BK, &Bs[t][pi * 4096 + ldst]);
  }

#define GSTEP(CUR, PRE, KT_PRE, DO_PRE, WAITIMM)                              \
  {                                                                           \
    __builtin_amdgcn_s_waitcnt(WAITIMM);                                      \
    __builtin_amdgcn_s_barrier();                                             \
    if (DO_PRE) {                                                             \
      load_lds16(Xb + aoff + (KT_PRE), &As[PRE][ldst]);                       \
      _Pragma("unroll")                                                       \
      for (int pi = 0; pi < 3; ++pi)                                          \
        load_lds16(Wb + boff + pi * 1048576 + (KT_PRE),                       \
                   &Bs[PRE][pi * 4096 + ldst]);                               \
    }                                                                         \
    short8 af[4], af2[4], af3[4], bfr[3][2];                                  \
    _Pragma("unroll")                                                         \
    for (int i = 0; i < 4; ++i) {                                             \
      int r = wr * 64 + i * 16 + frag_m;                                      \
      int q = sel ^ ((r >> 1) & 3);                                           \
      af[i] = *(const short8*)&As[CUR][r * BK + q * 8];                       \
      frag_pows(af[i], &af2[i], &af3[i]);                                     \
    }                                                                         \
    _Pragma("unroll")                                                         \
    for (int pi = 0; pi < 3; ++pi)                                            \
      _Pragma("unroll")                                                       \
      for (int j = 0; j < 2; ++j) {                                           \
        int r = wc * 32 + j * 16 + frag_m;                                    \
        int q = sel ^ ((r >> 1) & 3);                                         \
        bfr[pi][j] = *(const short8*)&Bs[CUR][pi * 4096 + r * BK + q * 8];    \
      }                                                                       \
    _Pragma("unroll")                                                         \
    for (int i = 0; i < 4; ++i)                                               \
      _Pragma("unroll")                                                       \
      for (int j = 0; j < 2; ++j) {                                           \
        acc[i][j] = __builtin_amdgcn_mfma_f32_16x16x32_bf16(                  \
            af[i],  bfr[0][j], acc[i][j], 0, 0, 0);                           \
        acc[i][j] = __builtin_amdgcn_mfma_f32_16x16x32_bf16(                  \
            af2[i], bfr[1][j], acc[i][j], 0, 0, 0);                           \
        acc[i][j] = __builtin_amdgcn_mfma_f32_16x16x32_bf16(                  \
            af3[i], bfr[2][j], acc[i][j], 0, 0, 0);                           \
      }                                                                       \
  }

  for (int t4 = 0; t4 < 28; t4 += 4) {         // steps 0..27, prefetch 3..30
    GSTEP(0, 3, (t4 + 3) * BK, 1, WAIT_VM8);
    GSTEP(1, 0, (t4 + 4) * BK, 1, WAIT_VM8);
    GSTEP(2, 1, (t4 + 5) * BK, 1, WAIT_VM8);
    GSTEP(3, 2, (t4 + 6) * BK, 1, WAIT_VM8);
  }
  GSTEP(0, 3, 31 * BK, 1, WAIT_VM8);           // step 28, prefetch tile 31
  GSTEP(1, 0, 0, 0, WAIT_VM8);                 // step 29 (t30,t31 in flight)
  GSTEP(2, 0, 0, 0, WAIT_VM4);                 // step 30 (t31 in flight)
  GSTEP(3, 0, 0, 0, WAIT_VM0);                 // step 31: drain
#undef GSTEP

  // epilogue: column sum/sumsq partials (no bias), un-normalized Y write.
  // colred aliased into As[0] (2 KB; buf0 last consumed step 28, 3 barriers
  // since).
  float* colred = (float*)&As[0][0];   // [wr*256 + {0:sum,128:sq} + col]
  float sv[2] = {0.f, 0.f}, sq[2] = {0.f, 0.f};
  #pragma unroll
  for (int j = 0; j < 2; ++j)
    #pragma unroll
    for (int i = 0; i < 4; ++i)
      #pragma unroll
      for (int r = 0; r < 4; ++r) {
        float v = acc[i][j][r];
        sv[j] += v; sq[j] += v * v;
      }
  #pragma unroll
  for (int j = 0; j < 2; ++j) {        // fold 4 sel-groups sharing a column
    sv[j] += __shfl_xor(sv[j], 16, 64); sv[j] += __shfl_xor(sv[j], 32, 64);
    sq[j] += __shfl_xor(sq[j], 16, 64); sq[j] += __shfl_xor(sq[j], 32, 64);
  }
  if (sel == 0) {
    #pragma unroll
    for (int j = 0; j < 2; ++j) {
      int cc = wc * 32 + j * 16 + frag_m;
      colred[wr * 256 + cc]       = sv[j];
      colred[wr * 256 + 128 + cc] = sq[j];
    }
  }
  // write Y (un-normalized) while colred settles
  const int drow = sel << 2;           // C/D: col=lane&15, row=(lane>>4)*4+r
  #pragma unroll
  for (int j = 0; j < 2; ++j) {
    int gc = col0 + wc * 32 + j * 16 + frag_m;
    #pragma unroll
    for (int i = 0; i < 4; ++i) {
      int gr = row0 + wr * 64 + i * 16 + drow;
      #pragma unroll
      for (int r = 0; r < 4; ++r)
        Y[(size_t)(gr + r) * OUTF + gc] = acc[i][j][r];
    }
  }
  __syncthreads();
  if (tid < BN) {
    psum[(size_t)by * OUTF + col0 + tid] = colred[tid]       + colred[256 + tid];
    psq [(size_t)by * OUTF + col0 + tid] = colred[128 + tid] + colred[384 + tid];
  }
}

// ---- 3. fused finalize + BN apply ------------------------------------------
__global__ void bn_fused(const float* __restrict__ psum, const float* __restrict__ psq,
                         const float* __restrict__ gamma, const float* __restrict__ beta,
                         float* __restrict__ Y) {
  __shared__ float sc[32], sh[32];
  const int c0 = blockIdx.x * 32;
  const int t = threadIdx.x;
  if (t < 32) {
    float s = 0.f, s2 = 0.f;
    #pragma unroll 8
    for (int p = 0; p < 32; ++p) {
      s  += psum[p * OUTF + c0 + t];
      s2 += psq [p * OUTF + c0 + t];
    }
    float mean = s * (1.0f / B_ROWS);
    float var  = s2 * (1.0f / B_ROWS) - mean * mean;
    float scale = gamma[c0 + t] * rsqrtf(var + BN_EPS);
    sc[t] = scale;
    sh[t] = beta[c0 + t] - mean * scale;
  }
  __syncthreads();
  const int f4c = t & 7;          // 8 float4 per 32-col slice
  const int rr  = t >> 3;         // 32 rows per sweep
  const int row0 = blockIdx.y * 256;
  float4* Y4 = (float4*)Y;
  const int cb = f4c * 4;
  float s0 = sc[cb], s1 = sc[cb+1], s2 = sc[cb+2], s3 = sc[cb+3];
  float h0 = sh[cb], h1 = sh[cb+1], h2 = sh[cb+2], h3 = sh[cb+3];
  #pragma unroll
  for (int it = 0; it < 8; ++it) {
    int row = row0 + it * 32 + rr;
    size_t idx = (size_t)row * 256 + (c0 >> 2) + f4c;
    float4 v = Y4[idx];
    v.x = v.x * s0 + h0; v.y = v.y * s1 + h1;
    v.z = v.z * s2 + h2; v.w = v.w * s3 + h3;
    Y4[idx] = v;
  }
}

extern "C" void kernel_launch(void* const* d_in, const int* in_sizes, int n_in,
                              void* d_out, int out_size, void* d_ws, size_t ws_size,
                              hipStream_t stream) {
  const float* x     = (const float*)d_in[0];
  const float* c1    = (const float*)d_in[1];
  const float* c2    = (const float*)d_in[2];
  const float* c3    = (const float*)d_in[3];
  // d_in[4] = bias: unused — per-column constant cancels exactly in BatchNorm
  const float* gamma = (const float*)d_in[5];
  const float* beta  = (const float*)d_in[6];
  float* out = (float*)d_out;
  char* ws = (char*)d_ws;

  short* Xb   = (short*)(ws);                          //  8,388,608 B
  short* Wb   = (short*)(ws + 8388608);                //  6,291,456 B (3 planes)
  float* psum = (float*)(ws + 14680064);               //    128 KB
  float* psq  = (float*)(ws + 14811136);               //    128 KB

  prep_all<<<5120, 256, 0, stream>>>((const float4*)x, (const float4*)c1,
                                     (const float4*)c2, (const float4*)c3,
                                     Xb, Wb);

  gemm_poly<<<256, 512, 0, stream>>>(Xb, Wb, out, psum, psq);

  dim3 bgrid(OUTF / 32, B_ROWS / 256);                 // (32, 16) = 512 blocks
  bn_fused<<<bgrid, 256, 0, stream>>>(psum, psq, gamma, beta, out);
}